// Round 9
// baseline (467.123 us; speedup 1.0000x reference)
//
#include <hip/hip_runtime.h>

#define DEVI __device__ __forceinline__

typedef short bf16x8 __attribute__((ext_vector_type(8)));
typedef short bf16x4 __attribute__((ext_vector_type(4)));
typedef float f32x4 __attribute__((ext_vector_type(4)));
typedef unsigned int u32x4 __attribute__((ext_vector_type(4)));
typedef unsigned short u16;

static constexpr int BB = 2, SS = 2048, HH = 1024, HD = 64;
static constexpr int BS = BB * SS;        // 4096 rows
static constexpr int HELEM = SS * HD;     // 131072 elems per head slice
// Q pre-scale: scores come out of MFMA in exp2 units: s*(1/32)*log2(e)
static constexpr float SC2Q = 0.045084220063365596f;

DEVI u16 f2bf(float f) {
  union { float f; unsigned u; } v; v.f = f;
  unsigned r = v.u + 0x7fffu + ((v.u >> 16) & 1u);
  return (u16)(r >> 16);
}
DEVI u16 f2bf_fast(float f) {  // round-half-up (1 fewer VALU op)
  union { float f; unsigned u; } v; v.f = f;
  return (u16)((v.u + 0x8000u) >> 16);
}

// async global->LDS, 16B per lane; lds ptr must be wave-uniform
DEVI void gl16(const u16* g, u16* l) {
  __builtin_amdgcn_global_load_lds(
      (const __attribute__((address_space(1))) unsigned int*)g,
      (__attribute__((address_space(3))) unsigned int*)l, 16, 0, 0);
}

// ---------------- f32 -> bf16 converters ----------------
__global__ __launch_bounds__(256) void cvt_inputs(const float* __restrict__ a,
                                                  const float* __restrict__ b,
                                                  u16* __restrict__ oa,
                                                  u16* __restrict__ ob) {
  const int NV = BS * HH / 4;
  int stride = gridDim.x * blockDim.x;
  for (int idx = blockIdx.x * blockDim.x + threadIdx.x; idx < 2 * NV; idx += stride) {
    int which = idx >= NV;
    int e = (which ? idx - NV : idx) * 4;
    const float* src = which ? b : a;
    u16* dst = which ? ob : oa;
    f32x4 v = *(const f32x4*)(src + e);
    unsigned long long pk = (unsigned long long)f2bf(v[0]) |
                            ((unsigned long long)f2bf(v[1]) << 16) |
                            ((unsigned long long)f2bf(v[2]) << 32) |
                            ((unsigned long long)f2bf(v[3]) << 48);
    *(unsigned long long*)(dst + e) = pk;
  }
}

// W [K,N] f32 -> WT [N,K] bf16
__global__ __launch_bounds__(256) void cvt_transpose_w(
    const float* __restrict__ w0, const float* __restrict__ w1,
    const float* __restrict__ w2, const float* __restrict__ w3,
    u16* __restrict__ t0, u16* __restrict__ t1, u16* __restrict__ t2,
    u16* __restrict__ t3) {
  const float* W; u16* T;
  switch (blockIdx.z) {
    case 0: W = w0; T = t0; break;
    case 1: W = w1; T = t1; break;
    case 2: W = w2; T = t2; break;
    default: W = w3; T = t3; break;
  }
  __shared__ float tile[64][65];
  int t = threadIdx.x;
  int bx = blockIdx.x, by = blockIdx.y;
  for (int h = 0; h < 4; ++h) {
    int r = (t >> 4) + h * 16;
    int c0 = (t & 15) * 4;
    f32x4 v = *(const f32x4*)(W + (size_t)(by * 64 + r) * HH + bx * 64 + c0);
    tile[r][c0 + 0] = v[0]; tile[r][c0 + 1] = v[1];
    tile[r][c0 + 2] = v[2]; tile[r][c0 + 3] = v[3];
  }
  __syncthreads();
  for (int h = 0; h < 4; ++h) {
    int nr = (t >> 4) + h * 16;
    int kc0 = (t & 15) * 4;
    unsigned long long pk = 0;
    for (int j = 0; j < 4; ++j)
      pk |= (unsigned long long)f2bf(tile[kc0 + j][nr]) << (16 * j);
    *(unsigned long long*)(T + (size_t)(bx * 64 + nr) * HH + by * 64 + kc0) = pk;
  }
}

// ------- 128x128 tile bf16 GEMM, global_load_lds staging (m97 pattern) -------
// OUTMODE: 0 = bf16 row-major, 1 = f32 row-major, 2 = bf16*SC2Q row-major
template <int OUTMODE>
DEVI void gemm_body(const u16* __restrict__ A, const u16* __restrict__ BT,
                    const float* __restrict__ bias, void* __restrict__ Cout,
                    int N, int K, int bm, int bn) {
  __shared__ u16 As[128 * 64];  // linear: row*64 + col (gload_lds requires)
  __shared__ u16 Bs[128 * 64];
  int tid = threadIdx.x, lane = tid & 63, wv = tid >> 6;
  int wr = wv >> 1, wc = wv & 1;
  int lq = lane & 15, g = lane >> 4;
  f32x4 acc[4][4] = {};
  const u16* Ab = A + (size_t)bm * 128 * K;
  const u16* Bb = BT + (size_t)bn * 128 * K;
  int srow = lane >> 3;
  int scol = (lane & 7) * 8;

  for (int k0 = 0; k0 < K; k0 += 64) {
#pragma unroll
    for (int h = 0; h < 4; ++h) {
      int ch = wv * 4 + h;
      int row = ch * 8 + srow;
      gl16(Ab + (size_t)row * K + k0 + scol, &As[ch * 512]);
      gl16(Bb + (size_t)row * K + k0 + scol, &Bs[ch * 512]);
    }
    __syncthreads();
#pragma unroll
    for (int ks = 0; ks < 2; ++ks) {
      int kk = ks * 32 + g * 8;
      bf16x8 af[4], bfr[4];
#pragma unroll
      for (int mt = 0; mt < 4; ++mt)
        af[mt] = *(const bf16x8*)(&As[(wr * 64 + mt * 16 + lq) * 64 + kk]);
#pragma unroll
      for (int nt = 0; nt < 4; ++nt)
        bfr[nt] = *(const bf16x8*)(&Bs[(wc * 64 + nt * 16 + lq) * 64 + kk]);
#pragma unroll
      for (int mt = 0; mt < 4; ++mt)
#pragma unroll
        for (int nt = 0; nt < 4; ++nt)
          acc[mt][nt] = __builtin_amdgcn_mfma_f32_16x16x32_bf16(
              af[mt], bfr[nt], acc[mt][nt], 0, 0, 0);
    }
    __syncthreads();
  }
#pragma unroll
  for (int mt = 0; mt < 4; ++mt)
#pragma unroll
    for (int nt = 0; nt < 4; ++nt) {
      int col = bn * 128 + wc * 64 + nt * 16 + lq;
      float bv = bias[col];
#pragma unroll
      for (int i = 0; i < 4; ++i) {
        int row = bm * 128 + wr * 64 + mt * 16 + g * 4 + i;
        float v = acc[mt][nt][i] + bv;
        if (OUTMODE == 1)
          ((float*)Cout)[(size_t)row * N + col] = v;
        else if (OUTMODE == 2)
          ((u16*)Cout)[(size_t)row * N + col] = f2bf(v * SC2Q);
        else
          ((u16*)Cout)[(size_t)row * N + col] = f2bf(v);
      }
    }
}

__global__ __launch_bounds__(256, 3) void qkv_gemm(
    const u16* __restrict__ X, const u16* __restrict__ C,
    const u16* __restrict__ WqT, const u16* __restrict__ WkT,
    const u16* __restrict__ WvT, const float* __restrict__ bq,
    const float* __restrict__ bk, const float* __restrict__ bv,
    u16* __restrict__ Qo, u16* __restrict__ Ko, u16* __restrict__ Vo) {
  if (blockIdx.z == 0)
    gemm_body<2>(X, WqT, bq, Qo, HH, HH, blockIdx.y, blockIdx.x);
  else if (blockIdx.z == 1)
    gemm_body<0>(C, WkT, bk, Ko, HH, HH, blockIdx.y, blockIdx.x);
  else
    gemm_body<0>(C, WvT, bv, Vo, HH, HH, blockIdx.y, blockIdx.x);
}

__global__ __launch_bounds__(256, 3) void out_gemm(const u16* __restrict__ Att,
                                                   const u16* __restrict__ WoT,
                                                   const float* __restrict__ bo,
                                                   float* __restrict__ out) {
  gemm_body<1>(Att, WoT, bo, out, HH, HH, blockIdx.y, blockIdx.x);
}

// ---------------- per-head permuted V transpose ----------------
// Head slice semantics = reference's DIRECT reshape: head slice = flat
// 131072-elem block read as [2048][64] row-major.
// Vt2[d][sigma] = V_head[kappa(sigma)][d]; within each 32-key chunk,
// kappa: sigma = 32c+8g+j -> 32c + 16*(j>>2) + 4*g + (j&3).
__global__ __launch_bounds__(256) void vtrans(const u16* __restrict__ V,
                                              u16* __restrict__ Vt2) {
  int head = blockIdx.y, kt = blockIdx.x;
  __shared__ u16 tile[64][72];
  int t = threadIdx.x;
  const u16* src = V + (size_t)head * HELEM + kt * 64 * HD;
  for (int h = 0; h < 2; ++h) {
    int r = (t >> 3) + h * 32;
    int c0 = (t & 7) * 8;
    *(u32x4*)(&tile[r][c0]) = *(const u32x4*)(src + r * HD + c0);
  }
  __syncthreads();
  u16* dst = Vt2 + (size_t)head * HELEM;
  for (int h = 0; h < 2; ++h) {
    int d = (t >> 3) + h * 32;
    int s0 = (t & 7) * 8;
    int base32 = s0 & ~31, g = (s0 >> 3) & 3;
    u16 tmp[8];
#pragma unroll
    for (int j = 0; j < 8; ++j)
      tmp[j] = tile[base32 + 16 * (j >> 2) + 4 * g + (j & 3)][d];
    *(u32x4*)(dst + (size_t)d * SS + kt * 64 + s0) = *(u32x4*)tmp;
  }
}

// ---------------- fused two-pass attention: NO LDS, NO BARRIERS ----------
// K/V per head = 256 KB each -> L2-resident (m169 lesson: don't LDS-stage
// L2-fit data). Each wave is fully independent: MFMA fragments load straight
// from global (L1/L2), K double-buffered in REGISTERS (static names), V loads
// issued BEFORE the P-stores so counted vmcnt waits never drain the store
// stream beyond BW pacing. Waves free-run -> one wave's store-pacing stall is
// hidden by other waves' compute. nontemporal P-stores keep K/V L2-resident.
// Q pre-scaled to exp2 units; nb via MFMA C-init -> P = one v_exp/element.
// Zero-shuffle P via kappa-permuted Vt2.
__global__ __launch_bounds__(256, 2) void attn_fused(
    const u16* __restrict__ Q, const u16* __restrict__ K,
    const u16* __restrict__ Vt2, float* __restrict__ attn_out,
    u16* __restrict__ Att) {
  int tid = threadIdx.x, lane = tid & 63, wv = tid >> 6;
  int g = lane >> 4, lq = lane & 15;
  int qt = blockIdx.x, bh = blockIdx.y;
  const u16* Qh = Q + (size_t)bh * HELEM + (qt * 64 + wv * 16) * HD;
  const u16* Kh = K + (size_t)bh * HELEM;
  const u16* Vh = Vt2 + (size_t)bh * HELEM;
  float* aout = attn_out + (size_t)(bh * SS + qt * 64 + wv * 16) * SS;

  // Q fragments (already in exp2 units)
  bf16x8 qf0 = *(const bf16x8*)(Qh + lq * HD + g * 8);
  bf16x8 qf1 = *(const bf16x8*)(Qh + lq * HD + 32 + g * 8);

  bf16x8 kfA[4][2], kfB[4][2];

#define LOADK(DST, KT)                                                     \
  do {                                                                     \
    const u16* kb_ = Kh + (size_t)(KT) * 64 * HD;                          \
    _Pragma("unroll") for (int t_ = 0; t_ < 4; ++t_)                       \
        _Pragma("unroll") for (int ks_ = 0; ks_ < 2; ++ks_)                \
            DST[t_][ks_] = *(const bf16x8*)(kb_ +                          \
                (size_t)(t_ * 16 + lq) * HD + ks_ * 32 + g * 8);           \
  } while (0)

#define QKMM(KF, ST)                                                       \
  do {                                                                     \
    _Pragma("unroll") for (int ks_ = 0; ks_ < 2; ++ks_) {                  \
      bf16x8 qf_ = ks_ ? qf1 : qf0;                                        \
      _Pragma("unroll") for (int t_ = 0; t_ < 4; ++t_)                     \
          ST[t_] = __builtin_amdgcn_mfma_f32_16x16x32_bf16(                \
              KF[t_][ks_], qf_, ST[t_], 0, 0, 0);                          \
    }                                                                      \
  } while (0)

  // ================= pass 1: row sums of exp2 (pure compute) =============
  float ps = 0.0f;
#define P1PHASE(KF_CUR, KF_NXT, KT, PRE)                                   \
  do {                                                                     \
    if (PRE) LOADK(KF_NXT, (KT) + 1);                                      \
    f32x4 st_[4] = {};                                                     \
    QKMM(KF_CUR, st_);                                                     \
    _Pragma("unroll") for (int t_ = 0; t_ < 4; ++t_)                       \
        _Pragma("unroll") for (int i_ = 0; i_ < 4; ++i_)                   \
            ps += __builtin_amdgcn_exp2f(st_[t_][i_]);                     \
  } while (0)

  LOADK(kfA, 0);
  for (int i = 0; i < 16; ++i) {
    P1PHASE(kfA, kfB, 2 * i, 1);
    P1PHASE(kfB, kfA, 2 * i + 1, (i < 15));
  }
  ps += __shfl_xor(ps, 16);
  ps += __shfl_xor(ps, 32);
  // v_log_f32 IS log2 -> nb = -log2(ps); p = exp2(st + nb)
  float nb = -__builtin_amdgcn_logf(ps);
  f32x4 nbv = {nb, nb, nb, nb};

  // ================= pass 2: write P, accumulate PV ======================
  f32x4 accv[4] = {};
#define P2PHASE(KF_CUR, KF_NXT, KT, PRE)                                   \
  do {                                                                     \
    if (PRE) LOADK(KF_NXT, (KT) + 1);                                      \
    bf16x8 vf_[2][4];                                                      \
    const u16* vb_ = Vh + (size_t)(KT) * 64;                               \
    _Pragma("unroll") for (int c_ = 0; c_ < 2; ++c_)                       \
        _Pragma("unroll") for (int nt_ = 0; nt_ < 4; ++nt_)                \
            vf_[c_][nt_] = *(const bf16x8*)(vb_ +                          \
                (size_t)(nt_ * 16 + lq) * SS + c_ * 32 + g * 8);           \
    f32x4 st_[4] = {nbv, nbv, nbv, nbv};                                   \
    QKMM(KF_CUR, st_);                                                     \
    alignas(16) bf16x4 pb_[4];                                             \
    _Pragma("unroll") for (int t_ = 0; t_ < 4; ++t_) {                     \
      f32x4 p_;                                                            \
      _Pragma("unroll") for (int i_ = 0; i_ < 4; ++i_)                     \
          p_[i_] = __builtin_amdgcn_exp2f(st_[t_][i_]);                    \
      __builtin_nontemporal_store(p_, (f32x4*)(aout + (size_t)lq * SS +    \
          (KT) * 64 + t_ * 16 + g * 4));                                   \
      _Pragma("unroll") for (int i_ = 0; i_ < 4; ++i_)                     \
          pb_[t_][i_] = (short)f2bf_fast(p_[i_]);                          \
    }                                                                      \
    _Pragma("unroll") for (int c_ = 0; c_ < 2; ++c_) {                     \
      bf16x8 pa_ = *(const bf16x8*)(&pb_[2 * c_]);                         \
      _Pragma("unroll") for (int nt_ = 0; nt_ < 4; ++nt_)                  \
          accv[nt_] = __builtin_amdgcn_mfma_f32_16x16x32_bf16(             \
              vf_[c_][nt_], pa_, accv[nt_], 0, 0, 0);                      \
    }                                                                      \
  } while (0)

  LOADK(kfA, 0);
  for (int i = 0; i < 16; ++i) {
    P2PHASE(kfA, kfB, 2 * i, 1);
    P2PHASE(kfB, kfA, 2 * i + 1, (i < 15));
  }

  // attended -> bf16 workspace (flat layout == reference reshape)
  u16* Ah = Att + (size_t)bh * HELEM + (qt * 64 + wv * 16) * HD;
#pragma unroll
  for (int nt = 0; nt < 4; ++nt) {
    bf16x4 ob;
#pragma unroll
    for (int i = 0; i < 4; ++i) ob[i] = (short)f2bf(accv[nt][i]);
    *(bf16x4*)(Ah + (size_t)lq * HD + nt * 16 + g * 4) = ob;
  }
}

// ---------------- host launch ----------------
extern "C" void kernel_launch(void* const* d_in, const int* in_sizes, int n_in,
                              void* d_out, int out_size, void* d_ws,
                              size_t ws_size, hipStream_t stream) {
  const float* inputs  = (const float*)d_in[0];
  const float* context = (const float*)d_in[1];
  const float* Wq = (const float*)d_in[2];
  const float* bq = (const float*)d_in[3];
  const float* Wk = (const float*)d_in[4];
  const float* bk = (const float*)d_in[5];
  const float* Wv = (const float*)d_in[6];
  const float* bv = (const float*)d_in[7];
  const float* Wo = (const float*)d_in[8];
  const float* bo = (const float*)d_in[9];
  float* out = (float*)d_out;
  float* attn = out + (size_t)BS * HH;

  char* ws = (char*)d_ws;
  u16* Xbf = (u16*)(ws + 0);          // 8 MB
  u16* Cbf = (u16*)(ws + 8388608);    // 8 MB
  u16* WqT = (u16*)(ws + 16777216);   // 2 MB each
  u16* WkT = (u16*)(ws + 18874368);
  u16* WvT = (u16*)(ws + 20971520);
  u16* WoT = (u16*)(ws + 23068672);
  u16* Qb  = (u16*)(ws + 25165824);   // 8 MB
  u16* Kb  = (u16*)(ws + 33554432);   // 8 MB
  u16* Vb  = (u16*)(ws + 41943040);   // 8 MB
  u16* Vtb = Cbf;                     // reuse: Cbf dead after qkv_gemm
  u16* Attb = Xbf;                    // reuse: Xbf dead after qkv

  cvt_inputs<<<dim3(2048), dim3(256), 0, stream>>>(inputs, context, Xbf, Cbf);
  cvt_transpose_w<<<dim3(16, 16, 4), dim3(256), 0, stream>>>(
      Wq, Wk, Wv, Wo, WqT, WkT, WvT, WoT);
  qkv_gemm<<<dim3(8, 32, 3), dim3(256), 0, stream>>>(
      Xbf, Cbf, WqT, WkT, WvT, bq, bk, bv, Qb, Kb, Vb);
  vtrans<<<dim3(32, 32), dim3(256), 0, stream>>>(Vb, Vtb);
  attn_fused<<<dim3(32, 32), dim3(256), 0, stream>>>(Qb, Kb, Vtb, attn, Attb);
  out_gemm<<<dim3(8, 32), dim3(256), 0, stream>>>(Attb, WoT, bo, out);
}

// Round 10
// 274.251 us; speedup vs baseline: 1.7033x; 1.7033x over previous
//
#include <hip/hip_runtime.h>

#define DEVI __device__ __forceinline__

typedef short bf16x8 __attribute__((ext_vector_type(8)));
typedef short bf16x4 __attribute__((ext_vector_type(4)));
typedef float f32x4 __attribute__((ext_vector_type(4)));
typedef unsigned int u32x4 __attribute__((ext_vector_type(4)));
typedef unsigned short u16;

static constexpr int BB = 2, SS = 2048, HH = 1024, HD = 64;
static constexpr int BS = BB * SS;        // 4096 rows
static constexpr int HELEM = SS * HD;     // 131072 elems per head slice
// Q pre-scale: scores come out of MFMA in exp2 units: s*(1/32)*log2(e)
static constexpr float SC2Q = 0.045084220063365596f;

DEVI u16 f2bf(float f) {
  union { float f; unsigned u; } v; v.f = f;
  unsigned r = v.u + 0x7fffu + ((v.u >> 16) & 1u);
  return (u16)(r >> 16);
}
DEVI u16 f2bf_fast(float f) {  // round-half-up (1 fewer VALU op)
  union { float f; unsigned u; } v; v.f = f;
  return (u16)((v.u + 0x8000u) >> 16);
}

// async global->LDS, 16B per lane; lds ptr must be wave-uniform
DEVI void gl16(const u16* g, u16* l) {
  __builtin_amdgcn_global_load_lds(
      (const __attribute__((address_space(1))) unsigned int*)g,
      (__attribute__((address_space(3))) unsigned int*)l, 16, 0, 0);
}

// raw barrier: wait LDS ops only — NEVER drains vmcnt
#define LDS_BARRIER() asm volatile("s_waitcnt lgkmcnt(0)\n\ts_barrier" ::: "memory")

// ---------------- f32 -> bf16 converters ----------------
__global__ __launch_bounds__(256) void cvt_inputs(const float* __restrict__ a,
                                                  const float* __restrict__ b,
                                                  u16* __restrict__ oa,
                                                  u16* __restrict__ ob) {
  const int NV = BS * HH / 4;
  int stride = gridDim.x * blockDim.x;
  for (int idx = blockIdx.x * blockDim.x + threadIdx.x; idx < 2 * NV; idx += stride) {
    int which = idx >= NV;
    int e = (which ? idx - NV : idx) * 4;
    const float* src = which ? b : a;
    u16* dst = which ? ob : oa;
    f32x4 v = *(const f32x4*)(src + e);
    unsigned long long pk = (unsigned long long)f2bf(v[0]) |
                            ((unsigned long long)f2bf(v[1]) << 16) |
                            ((unsigned long long)f2bf(v[2]) << 32) |
                            ((unsigned long long)f2bf(v[3]) << 48);
    *(unsigned long long*)(dst + e) = pk;
  }
}

// W [K,N] f32 -> WT [N,K] bf16
__global__ __launch_bounds__(256) void cvt_transpose_w(
    const float* __restrict__ w0, const float* __restrict__ w1,
    const float* __restrict__ w2, const float* __restrict__ w3,
    u16* __restrict__ t0, u16* __restrict__ t1, u16* __restrict__ t2,
    u16* __restrict__ t3) {
  const float* W; u16* T;
  switch (blockIdx.z) {
    case 0: W = w0; T = t0; break;
    case 1: W = w1; T = t1; break;
    case 2: W = w2; T = t2; break;
    default: W = w3; T = t3; break;
  }
  __shared__ float tile[64][65];
  int t = threadIdx.x;
  int bx = blockIdx.x, by = blockIdx.y;
  for (int h = 0; h < 4; ++h) {
    int r = (t >> 4) + h * 16;
    int c0 = (t & 15) * 4;
    f32x4 v = *(const f32x4*)(W + (size_t)(by * 64 + r) * HH + bx * 64 + c0);
    tile[r][c0 + 0] = v[0]; tile[r][c0 + 1] = v[1];
    tile[r][c0 + 2] = v[2]; tile[r][c0 + 3] = v[3];
  }
  __syncthreads();
  for (int h = 0; h < 4; ++h) {
    int nr = (t >> 4) + h * 16;
    int kc0 = (t & 15) * 4;
    unsigned long long pk = 0;
    for (int j = 0; j < 4; ++j)
      pk |= (unsigned long long)f2bf(tile[kc0 + j][nr]) << (16 * j);
    *(unsigned long long*)(T + (size_t)(bx * 64 + nr) * HH + by * 64 + kc0) = pk;
  }
}

// ------- 128x128 tile bf16 GEMM, global_load_lds staging (m97 pattern) -------
// OUTMODE: 0 = bf16 row-major, 1 = f32 row-major, 2 = bf16*SC2Q row-major
template <int OUTMODE>
DEVI void gemm_body(const u16* __restrict__ A, const u16* __restrict__ BT,
                    const float* __restrict__ bias, void* __restrict__ Cout,
                    int N, int K, int bm, int bn) {
  __shared__ u16 As[128 * 64];  // linear: row*64 + col (gload_lds requires)
  __shared__ u16 Bs[128 * 64];
  int tid = threadIdx.x, lane = tid & 63, wv = tid >> 6;
  int wr = wv >> 1, wc = wv & 1;
  int lq = lane & 15, g = lane >> 4;
  f32x4 acc[4][4] = {};
  const u16* Ab = A + (size_t)bm * 128 * K;
  const u16* Bb = BT + (size_t)bn * 128 * K;
  int srow = lane >> 3;
  int scol = (lane & 7) * 8;

  for (int k0 = 0; k0 < K; k0 += 64) {
#pragma unroll
    for (int h = 0; h < 4; ++h) {
      int ch = wv * 4 + h;
      int row = ch * 8 + srow;
      gl16(Ab + (size_t)row * K + k0 + scol, &As[ch * 512]);
      gl16(Bb + (size_t)row * K + k0 + scol, &Bs[ch * 512]);
    }
    __syncthreads();
#pragma unroll
    for (int ks = 0; ks < 2; ++ks) {
      int kk = ks * 32 + g * 8;
      bf16x8 af[4], bfr[4];
#pragma unroll
      for (int mt = 0; mt < 4; ++mt)
        af[mt] = *(const bf16x8*)(&As[(wr * 64 + mt * 16 + lq) * 64 + kk]);
#pragma unroll
      for (int nt = 0; nt < 4; ++nt)
        bfr[nt] = *(const bf16x8*)(&Bs[(wc * 64 + nt * 16 + lq) * 64 + kk]);
#pragma unroll
      for (int mt = 0; mt < 4; ++mt)
#pragma unroll
        for (int nt = 0; nt < 4; ++nt)
          acc[mt][nt] = __builtin_amdgcn_mfma_f32_16x16x32_bf16(
              af[mt], bfr[nt], acc[mt][nt], 0, 0, 0);
    }
    __syncthreads();
  }
#pragma unroll
  for (int mt = 0; mt < 4; ++mt)
#pragma unroll
    for (int nt = 0; nt < 4; ++nt) {
      int col = bn * 128 + wc * 64 + nt * 16 + lq;
      float bv = bias[col];
#pragma unroll
      for (int i = 0; i < 4; ++i) {
        int row = bm * 128 + wr * 64 + mt * 16 + g * 4 + i;
        float v = acc[mt][nt][i] + bv;
        if (OUTMODE == 1)
          ((float*)Cout)[(size_t)row * N + col] = v;
        else if (OUTMODE == 2)
          ((u16*)Cout)[(size_t)row * N + col] = f2bf(v * SC2Q);
        else
          ((u16*)Cout)[(size_t)row * N + col] = f2bf(v);
      }
    }
}

__global__ __launch_bounds__(256, 3) void qkv_gemm(
    const u16* __restrict__ X, const u16* __restrict__ C,
    const u16* __restrict__ WqT, const u16* __restrict__ WkT,
    const u16* __restrict__ WvT, const float* __restrict__ bq,
    const float* __restrict__ bk, const float* __restrict__ bv,
    u16* __restrict__ Qo, u16* __restrict__ Ko, u16* __restrict__ Vo) {
  if (blockIdx.z == 0)
    gemm_body<2>(X, WqT, bq, Qo, HH, HH, blockIdx.y, blockIdx.x);
  else if (blockIdx.z == 1)
    gemm_body<0>(C, WkT, bk, Ko, HH, HH, blockIdx.y, blockIdx.x);
  else
    gemm_body<0>(C, WvT, bv, Vo, HH, HH, blockIdx.y, blockIdx.x);
}

__global__ __launch_bounds__(256, 3) void out_gemm(const u16* __restrict__ Att,
                                                   const u16* __restrict__ WoT,
                                                   const float* __restrict__ bo,
                                                   float* __restrict__ out) {
  gemm_body<1>(Att, WoT, bo, out, HH, HH, blockIdx.y, blockIdx.x);
}

// ---------------- per-head permuted V transpose ----------------
// Vt2[d][sigma] = V_head[kappa(sigma)][d]; within each 32-key chunk,
// kappa: sigma = 32c+8g+j -> 32c + 16*(j>>2) + 4*g + (j&3).
__global__ __launch_bounds__(256) void vtrans(const u16* __restrict__ V,
                                              u16* __restrict__ Vt2) {
  int head = blockIdx.y, kt = blockIdx.x;
  __shared__ u16 tile[64][72];
  int t = threadIdx.x;
  const u16* src = V + (size_t)head * HELEM + kt * 64 * HD;
  for (int h = 0; h < 2; ++h) {
    int r = (t >> 3) + h * 32;
    int c0 = (t & 7) * 8;
    *(u32x4*)(&tile[r][c0]) = *(const u32x4*)(src + r * HD + c0);
  }
  __syncthreads();
  u16* dst = Vt2 + (size_t)head * HELEM;
  for (int h = 0; h < 2; ++h) {
    int d = (t >> 3) + h * 32;
    int s0 = (t & 7) * 8;
    int base32 = s0 & ~31, g = (s0 >> 3) & 3;
    u16 tmp[8];
#pragma unroll
    for (int j = 0; j < 8; ++j)
      tmp[j] = tile[base32 + 16 * (j >> 2) + 4 * g + (j & 3)][d];
    *(u32x4*)(dst + (size_t)d * SS + kt * 64 + s0) = *(u32x4*)tmp;
  }
}

// ---------------- attention core: single pass, NO P-store ----------------
// R7-proven LDS/barrier structure. Computes unnormalized O = sum exp2(s)*V
// and ps = sum exp2(s) together; writes Att = O/ps (bf16) and nb = -log2(ps).
// No store stream in the loop -> load-waits are cheap.
__global__ __launch_bounds__(256, 2) void attn_core(
    const u16* __restrict__ Q, const u16* __restrict__ K,
    const u16* __restrict__ Vt2, float* __restrict__ nbuf,
    u16* __restrict__ Att) {
  __shared__ u16 Ks[2][128][72];
  __shared__ u16 Vs[2][64][136];
  int tid = threadIdx.x, lane = tid & 63, wv = tid >> 6;
  int g = lane >> 4, lq = lane & 15;
  int qt = blockIdx.x, bh = blockIdx.y;
  const u16* Qh = Q + (size_t)bh * HELEM + (qt * 64 + wv * 16) * HD;
  const u16* Kh = K + (size_t)bh * HELEM;
  const u16* Vh = Vt2 + (size_t)bh * HELEM;

  bf16x8 qf0 = *(const bf16x8*)(Qh + lq * HD + g * 8);
  bf16x8 qf1 = *(const bf16x8*)(Qh + lq * HD + 32 + g * 8);

  int k_r = tid >> 3, k_c = (tid & 7) * 8;
  int v_r = tid >> 4, v_c = (tid & 15) * 8;
  u32x4 krg[4], vrg[4];

  f32x4 accv[4] = {};
  float ps = 0.0f;
#pragma unroll
  for (int h = 0; h < 4; ++h) {
    krg[h] = *(const u32x4*)(Kh + (size_t)(h * 32 + k_r) * HD + k_c);
    vrg[h] = *(const u32x4*)(Vh + (size_t)(h * 16 + v_r) * SS + v_c);
  }
#pragma unroll
  for (int h = 0; h < 4; ++h) {
    *(u32x4*)(&Ks[0][h * 32 + k_r][k_c]) = krg[h];
    *(u32x4*)(&Vs[0][h * 16 + v_r][v_c]) = vrg[h];
  }
  LDS_BARRIER();

  for (int kt = 0; kt < 16; ++kt) {
    int cur = kt & 1;
    if (kt < 15) {
      const u16* kb = Kh + (size_t)(kt + 1) * 128 * HD;
      const u16* vb = Vh + (size_t)(kt + 1) * 128;
#pragma unroll
      for (int h = 0; h < 4; ++h) {
        krg[h] = *(const u32x4*)(kb + (size_t)(h * 32 + k_r) * HD + k_c);
        vrg[h] = *(const u32x4*)(vb + (size_t)(h * 16 + v_r) * SS + v_c);
      }
    }
    f32x4 st[8] = {};
#pragma unroll
    for (int ks = 0; ks < 2; ++ks) {
      bf16x8 qf = ks ? qf1 : qf0;
      int kk = ks * 32 + g * 8;
#pragma unroll
      for (int t = 0; t < 8; ++t) {
        bf16x8 kf = *(const bf16x8*)(&Ks[cur][t * 16 + lq][kk]);
        st[t] = __builtin_amdgcn_mfma_f32_16x16x32_bf16(kf, qf, st[t], 0, 0, 0);
      }
    }
    // pa = exp2(st) UNNORMALIZED (bounded ~[1e-2, 150]); ps accumulates
    alignas(16) bf16x4 pb[8];
#pragma unroll
    for (int t = 0; t < 8; ++t) {
      f32x4 p;
#pragma unroll
      for (int i = 0; i < 4; ++i) {
        p[i] = __builtin_amdgcn_exp2f(st[t][i]);
        ps += p[i];
      }
#pragma unroll
      for (int i = 0; i < 4; ++i) pb[t][i] = (short)f2bf_fast(p[i]);
    }
#pragma unroll
    for (int c = 0; c < 4; ++c) {
      bf16x8 pa = *(const bf16x8*)(&pb[2 * c]);
#pragma unroll
      for (int nt = 0; nt < 4; ++nt) {
        bf16x8 vf = *(const bf16x8*)(&Vs[cur][nt * 16 + lq][c * 32 + g * 8]);
        accv[nt] = __builtin_amdgcn_mfma_f32_16x16x32_bf16(vf, pa, accv[nt], 0, 0, 0);
      }
    }
    if (kt < 15) {
#pragma unroll
      for (int h = 0; h < 4; ++h) {
        *(u32x4*)(&Ks[cur ^ 1][h * 32 + k_r][k_c]) = krg[h];
        *(u32x4*)(&Vs[cur ^ 1][h * 16 + v_r][v_c]) = vrg[h];
      }
    }
    LDS_BARRIER();
  }

  ps += __shfl_xor(ps, 16);
  ps += __shfl_xor(ps, 32);
  float rinv = 1.0f / ps;
  // v_log_f32 IS log2 -> nb = -log2(ps)
  if (lane < 16)
    nbuf[(size_t)bh * SS + qt * 64 + wv * 16 + lq] = -__builtin_amdgcn_logf(ps);

  u16* Ah = Att + (size_t)bh * HELEM + (qt * 64 + wv * 16) * HD;
#pragma unroll
  for (int nt = 0; nt < 4; ++nt) {
    bf16x4 ob;
#pragma unroll
    for (int i = 0; i < 4; ++i) ob[i] = (short)f2bf(accv[nt][i] * rinv);
    *(bf16x4*)(Ah + (size_t)lq * HD + nt * 16 + g * 4) = ob;
  }
}

// ---------------- P writer: pure store stream ----------------
// Block = (key-eighth e, head bh): 256 keys staged in LDS once; each of the
// 8 waves owns 256 q-rows whose Q-fragments + nb live ENTIRELY in registers
// (full unroll -> static indexing). The main loop's only VMEM ops are the
// P-stores -> no vmcnt load-waits ever drain the stream; it runs at HBM pace.
__global__ __launch_bounds__(512, 2) void p_write(
    const u16* __restrict__ Kb, const u16* __restrict__ Qb,
    const float* __restrict__ nbuf, float* __restrict__ attn_out) {
  __shared__ u16 Ks[256 * 64];  // linear [256 keys][64 d]
  int tid = threadIdx.x, lane = tid & 63, wv = tid >> 6;
  int g = lane >> 4, lq = lane & 15;
  int e = blockIdx.x, bh = blockIdx.y;
  const u16* Kh = Kb + (size_t)bh * HELEM + (size_t)e * 256 * HD;
  const u16* Qh = Qb + (size_t)bh * HELEM;
  float* aout = attn_out + (size_t)bh * SS * SS + e * 256;

  // stage K slice (32 KB) via global_load_lds: 32 chunks of 8 rows
  int srow = lane >> 3, scol = (lane & 7) * 8;
#pragma unroll
  for (int h = 0; h < 4; ++h) {
    int ch = h * 8 + wv;
    gl16(Kh + (size_t)(ch * 8 + srow) * HD + scol, &Ks[ch * 512]);
  }
  // preload this wave's 256 q-rows of Q-fragments + nb into registers
  int q0 = wv * 256;
  bf16x8 qf[16][2];
  float nbq[16];
#pragma unroll
  for (int qi = 0; qi < 16; ++qi) {
#pragma unroll
    for (int ks = 0; ks < 2; ++ks)
      qf[qi][ks] = *(const bf16x8*)(Qh + (size_t)(q0 + qi * 16 + lq) * HD +
                                    ks * 32 + g * 8);
    nbq[qi] = nbuf[(size_t)bh * SS + q0 + qi * 16 + lq];
  }
  __syncthreads();  // drains all prologue VMEM (vmcnt 0) once

  // pure store-stream loop (static qf/nbq indices via full unroll)
#pragma unroll
  for (int qi = 0; qi < 16; ++qi) {
    f32x4 nbv = {nbq[qi], nbq[qi], nbq[qi], nbq[qi]};
    float* arow = aout + (size_t)(q0 + qi * 16 + lq) * SS;
#pragma unroll
    for (int kc = 0; kc < 4; ++kc) {
      f32x4 st[4] = {nbv, nbv, nbv, nbv};
#pragma unroll
      for (int ks = 0; ks < 2; ++ks)
#pragma unroll
        for (int t = 0; t < 4; ++t) {
          bf16x8 kf = *(const bf16x8*)(
              &Ks[(kc * 64 + t * 16 + lq) * 64 + ks * 32 + g * 8]);
          st[t] = __builtin_amdgcn_mfma_f32_16x16x32_bf16(kf, qf[qi][ks],
                                                          st[t], 0, 0, 0);
        }
#pragma unroll
      for (int t = 0; t < 4; ++t) {
        f32x4 p;
#pragma unroll
        for (int i = 0; i < 4; ++i) p[i] = __builtin_amdgcn_exp2f(st[t][i]);
        *(f32x4*)(arow + kc * 64 + t * 16 + g * 4) = p;
      }
    }
  }
}

// ---------------- host launch ----------------
extern "C" void kernel_launch(void* const* d_in, const int* in_sizes, int n_in,
                              void* d_out, int out_size, void* d_ws,
                              size_t ws_size, hipStream_t stream) {
  const float* inputs  = (const float*)d_in[0];
  const float* context = (const float*)d_in[1];
  const float* Wq = (const float*)d_in[2];
  const float* bq = (const float*)d_in[3];
  const float* Wk = (const float*)d_in[4];
  const float* bk = (const float*)d_in[5];
  const float* Wv = (const float*)d_in[6];
  const float* bv = (const float*)d_in[7];
  const float* Wo = (const float*)d_in[8];
  const float* bo = (const float*)d_in[9];
  float* out = (float*)d_out;
  float* attn = out + (size_t)BS * HH;

  char* ws = (char*)d_ws;
  u16* Xbf = (u16*)(ws + 0);          // 8 MB
  u16* Cbf = (u16*)(ws + 8388608);    // 8 MB
  u16* WqT = (u16*)(ws + 16777216);   // 2 MB each
  u16* WkT = (u16*)(ws + 18874368);
  u16* WvT = (u16*)(ws + 20971520);
  u16* WoT = (u16*)(ws + 23068672);
  u16* Qb  = (u16*)(ws + 25165824);   // 8 MB
  u16* Kb  = (u16*)(ws + 33554432);   // 8 MB
  u16* Vb  = (u16*)(ws + 41943040);   // 8 MB
  u16* Vtb = Cbf;                         // reuse: Cbf dead after qkv_gemm
  float* nbuf = (float*)(ws + 18874368);  // reuse WkT slot (dead after qkv)
  u16* Attb = Xbf;                        // reuse: Xbf dead after qkv

  cvt_inputs<<<dim3(2048), dim3(256), 0, stream>>>(inputs, context, Xbf, Cbf);
  cvt_transpose_w<<<dim3(16, 16, 4), dim3(256), 0, stream>>>(
      Wq, Wk, Wv, Wo, WqT, WkT, WvT, WoT);
  qkv_gemm<<<dim3(8, 32, 3), dim3(256), 0, stream>>>(
      Xbf, Cbf, WqT, WkT, WvT, bq, bk, bv, Qb, Kb, Vb);
  vtrans<<<dim3(32, 32), dim3(256), 0, stream>>>(Vb, Vtb);
  attn_core<<<dim3(32, 32), dim3(256), 0, stream>>>(Qb, Kb, Vtb, nbuf, Attb);
  p_write<<<dim3(8, 32), dim3(512), 0, stream>>>(Kb, Qb, nbuf, attn);
  out_gemm<<<dim3(8, 32), dim3(256), 0, stream>>>(Attb, WoT, bo, out);
}

// Round 11
// 267.493 us; speedup vs baseline: 1.7463x; 1.0253x over previous
//
#include <hip/hip_runtime.h>

#define DEVI __device__ __forceinline__

typedef short bf16x8 __attribute__((ext_vector_type(8)));
typedef short bf16x4 __attribute__((ext_vector_type(4)));
typedef float f32x4 __attribute__((ext_vector_type(4)));
typedef unsigned int u32x4 __attribute__((ext_vector_type(4)));
typedef unsigned short u16;

static constexpr int BB = 2, SS = 2048, HH = 1024, HD = 64;
static constexpr int BS = BB * SS;        // 4096 rows
static constexpr int HELEM = SS * HD;     // 131072 elems per head slice
// Q pre-scale: scores come out of MFMA in exp2 units: s*(1/32)*log2(e)
static constexpr float SC2Q = 0.045084220063365596f;

DEVI u16 f2bf(float f) {
  union { float f; unsigned u; } v; v.f = f;
  unsigned r = v.u + 0x7fffu + ((v.u >> 16) & 1u);
  return (u16)(r >> 16);
}
DEVI u16 f2bf_fast(float f) {  // round-half-up (1 fewer VALU op)
  union { float f; unsigned u; } v; v.f = f;
  return (u16)((v.u + 0x8000u) >> 16);
}

// async global->LDS, 16B per lane; lds ptr must be wave-uniform
DEVI void gl16(const u16* g, u16* l) {
  __builtin_amdgcn_global_load_lds(
      (const __attribute__((address_space(1))) unsigned int*)g,
      (__attribute__((address_space(3))) unsigned int*)l, 16, 0, 0);
}

// raw barrier: wait LDS ops only — NEVER drains vmcnt
#define LDS_BARRIER() asm volatile("s_waitcnt lgkmcnt(0)\n\ts_barrier" ::: "memory")

// ---------------- f32 -> bf16 converters ----------------
__global__ __launch_bounds__(256) void cvt_inputs(const float* __restrict__ a,
                                                  const float* __restrict__ b,
                                                  u16* __restrict__ oa,
                                                  u16* __restrict__ ob) {
  const int NV = BS * HH / 4;
  int stride = gridDim.x * blockDim.x;
  for (int idx = blockIdx.x * blockDim.x + threadIdx.x; idx < 2 * NV; idx += stride) {
    int which = idx >= NV;
    int e = (which ? idx - NV : idx) * 4;
    const float* src = which ? b : a;
    u16* dst = which ? ob : oa;
    f32x4 v = *(const f32x4*)(src + e);
    unsigned long long pk = (unsigned long long)f2bf(v[0]) |
                            ((unsigned long long)f2bf(v[1]) << 16) |
                            ((unsigned long long)f2bf(v[2]) << 32) |
                            ((unsigned long long)f2bf(v[3]) << 48);
    *(unsigned long long*)(dst + e) = pk;
  }
}

// W [K,N] f32 -> WT [N,K] bf16
__global__ __launch_bounds__(256) void cvt_transpose_w(
    const float* __restrict__ w0, const float* __restrict__ w1,
    const float* __restrict__ w2, const float* __restrict__ w3,
    u16* __restrict__ t0, u16* __restrict__ t1, u16* __restrict__ t2,
    u16* __restrict__ t3) {
  const float* W; u16* T;
  switch (blockIdx.z) {
    case 0: W = w0; T = t0; break;
    case 1: W = w1; T = t1; break;
    case 2: W = w2; T = t2; break;
    default: W = w3; T = t3; break;
  }
  __shared__ float tile[64][65];
  int t = threadIdx.x;
  int bx = blockIdx.x, by = blockIdx.y;
  for (int h = 0; h < 4; ++h) {
    int r = (t >> 4) + h * 16;
    int c0 = (t & 15) * 4;
    f32x4 v = *(const f32x4*)(W + (size_t)(by * 64 + r) * HH + bx * 64 + c0);
    tile[r][c0 + 0] = v[0]; tile[r][c0 + 1] = v[1];
    tile[r][c0 + 2] = v[2]; tile[r][c0 + 3] = v[3];
  }
  __syncthreads();
  for (int h = 0; h < 4; ++h) {
    int nr = (t >> 4) + h * 16;
    int kc0 = (t & 15) * 4;
    unsigned long long pk = 0;
    for (int j = 0; j < 4; ++j)
      pk |= (unsigned long long)f2bf(tile[kc0 + j][nr]) << (16 * j);
    *(unsigned long long*)(T + (size_t)(bx * 64 + nr) * HH + by * 64 + kc0) = pk;
  }
}

// ------- 128x128 tile bf16 GEMM, global_load_lds staging (m97 pattern) -------
// OUTMODE: 0 = bf16 row-major, 1 = f32 row-major, 2 = bf16*SC2Q row-major
template <int OUTMODE>
DEVI void gemm_body(const u16* __restrict__ A, const u16* __restrict__ BT,
                    const float* __restrict__ bias, void* __restrict__ Cout,
                    int N, int K, int bm, int bn) {
  __shared__ u16 As[128 * 64];  // linear: row*64 + col (gload_lds requires)
  __shared__ u16 Bs[128 * 64];
  int tid = threadIdx.x, lane = tid & 63, wv = tid >> 6;
  int wr = wv >> 1, wc = wv & 1;
  int lq = lane & 15, g = lane >> 4;
  f32x4 acc[4][4] = {};
  const u16* Ab = A + (size_t)bm * 128 * K;
  const u16* Bb = BT + (size_t)bn * 128 * K;
  int srow = lane >> 3;
  int scol = (lane & 7) * 8;

  for (int k0 = 0; k0 < K; k0 += 64) {
#pragma unroll
    for (int h = 0; h < 4; ++h) {
      int ch = wv * 4 + h;
      int row = ch * 8 + srow;
      gl16(Ab + (size_t)row * K + k0 + scol, &As[ch * 512]);
      gl16(Bb + (size_t)row * K + k0 + scol, &Bs[ch * 512]);
    }
    __syncthreads();
#pragma unroll
    for (int ks = 0; ks < 2; ++ks) {
      int kk = ks * 32 + g * 8;
      bf16x8 af[4], bfr[4];
#pragma unroll
      for (int mt = 0; mt < 4; ++mt)
        af[mt] = *(const bf16x8*)(&As[(wr * 64 + mt * 16 + lq) * 64 + kk]);
#pragma unroll
      for (int nt = 0; nt < 4; ++nt)
        bfr[nt] = *(const bf16x8*)(&Bs[(wc * 64 + nt * 16 + lq) * 64 + kk]);
#pragma unroll
      for (int mt = 0; mt < 4; ++mt)
#pragma unroll
        for (int nt = 0; nt < 4; ++nt)
          acc[mt][nt] = __builtin_amdgcn_mfma_f32_16x16x32_bf16(
              af[mt], bfr[nt], acc[mt][nt], 0, 0, 0);
    }
    __syncthreads();
  }
#pragma unroll
  for (int mt = 0; mt < 4; ++mt)
#pragma unroll
    for (int nt = 0; nt < 4; ++nt) {
      int col = bn * 128 + wc * 64 + nt * 16 + lq;
      float bv = bias[col];
#pragma unroll
      for (int i = 0; i < 4; ++i) {
        int row = bm * 128 + wr * 64 + mt * 16 + g * 4 + i;
        float v = acc[mt][nt][i] + bv;
        if (OUTMODE == 1)
          ((float*)Cout)[(size_t)row * N + col] = v;
        else if (OUTMODE == 2)
          ((u16*)Cout)[(size_t)row * N + col] = f2bf(v * SC2Q);
        else
          ((u16*)Cout)[(size_t)row * N + col] = f2bf(v);
      }
    }
}

__global__ __launch_bounds__(256, 3) void qkv_gemm(
    const u16* __restrict__ X, const u16* __restrict__ C,
    const u16* __restrict__ WqT, const u16* __restrict__ WkT,
    const u16* __restrict__ WvT, const float* __restrict__ bq,
    const float* __restrict__ bk, const float* __restrict__ bv,
    u16* __restrict__ Qo, u16* __restrict__ Ko, u16* __restrict__ Vo) {
  if (blockIdx.z == 0)
    gemm_body<2>(X, WqT, bq, Qo, HH, HH, blockIdx.y, blockIdx.x);
  else if (blockIdx.z == 1)
    gemm_body<0>(C, WkT, bk, Ko, HH, HH, blockIdx.y, blockIdx.x);
  else
    gemm_body<0>(C, WvT, bv, Vo, HH, HH, blockIdx.y, blockIdx.x);
}

__global__ __launch_bounds__(256, 3) void out_gemm(const u16* __restrict__ Att,
                                                   const u16* __restrict__ WoT,
                                                   const float* __restrict__ bo,
                                                   float* __restrict__ out) {
  gemm_body<1>(Att, WoT, bo, out, HH, HH, blockIdx.y, blockIdx.x);
}

// ---------------- per-head permuted V transpose ----------------
// Vt2[d][sigma] = V_head[kappa(sigma)][d]; within each 32-key chunk,
// kappa: sigma = 32c+8g+j -> 32c + 16*(j>>2) + 4*g + (j&3).
__global__ __launch_bounds__(256) void vtrans(const u16* __restrict__ V,
                                              u16* __restrict__ Vt2) {
  int head = blockIdx.y, kt = blockIdx.x;
  __shared__ u16 tile[64][72];
  int t = threadIdx.x;
  const u16* src = V + (size_t)head * HELEM + kt * 64 * HD;
  for (int h = 0; h < 2; ++h) {
    int r = (t >> 3) + h * 32;
    int c0 = (t & 7) * 8;
    *(u32x4*)(&tile[r][c0]) = *(const u32x4*)(src + r * HD + c0);
  }
  __syncthreads();
  u16* dst = Vt2 + (size_t)head * HELEM;
  for (int h = 0; h < 2; ++h) {
    int d = (t >> 3) + h * 32;
    int s0 = (t & 7) * 8;
    int base32 = s0 & ~31, g = (s0 >> 3) & 3;
    u16 tmp[8];
#pragma unroll
    for (int j = 0; j < 8; ++j)
      tmp[j] = tile[base32 + 16 * (j >> 2) + 4 * g + (j & 3)][d];
    *(u32x4*)(dst + (size_t)d * SS + kt * 64 + s0) = *(u32x4*)tmp;
  }
}

// ---------------- attention core: single pass, NO P-store, KVBLK=64 --------
// Computes unnormalized O = sum exp2(s)*V and ps = sum exp2(s) together;
// writes Att = O/ps (bf16) and nb = -log2(ps). LDS 36 KB -> 4 blocks/CU
// (vs R10's 2): the serial QK->exp->PV chain now has 4 waves/SIMD to hide
// under. No store stream in the loop -> load-waits are cheap.
__global__ __launch_bounds__(256, 4) void attn_core(
    const u16* __restrict__ Q, const u16* __restrict__ K,
    const u16* __restrict__ Vt2, float* __restrict__ nbuf,
    u16* __restrict__ Att) {
  __shared__ u16 Ks[2][64][72];
  __shared__ u16 Vs[2][64][72];
  int tid = threadIdx.x, lane = tid & 63, wv = tid >> 6;
  int g = lane >> 4, lq = lane & 15;
  int qt = blockIdx.x, bh = blockIdx.y;
  const u16* Qh = Q + (size_t)bh * HELEM + (qt * 64 + wv * 16) * HD;
  const u16* Kh = K + (size_t)bh * HELEM;
  const u16* Vh = Vt2 + (size_t)bh * HELEM;

  bf16x8 qf0 = *(const bf16x8*)(Qh + lq * HD + g * 8);
  bf16x8 qf1 = *(const bf16x8*)(Qh + lq * HD + 32 + g * 8);

  int s_r = tid >> 3, s_c = (tid & 7) * 8;  // K/V stage: rows s_r + h*32
  u32x4 krg[2], vrg[2];

  f32x4 accv[4] = {};
  float ps = 0.0f;
#pragma unroll
  for (int h = 0; h < 2; ++h) {
    krg[h] = *(const u32x4*)(Kh + (size_t)(h * 32 + s_r) * HD + s_c);
    vrg[h] = *(const u32x4*)(Vh + (size_t)(h * 32 + s_r) * SS + s_c);
  }
#pragma unroll
  for (int h = 0; h < 2; ++h) {
    *(u32x4*)(&Ks[0][h * 32 + s_r][s_c]) = krg[h];
    *(u32x4*)(&Vs[0][h * 32 + s_r][s_c]) = vrg[h];
  }
  LDS_BARRIER();

  for (int kt = 0; kt < 32; ++kt) {
    int cur = kt & 1;
    if (kt < 31) {
      const u16* kb = Kh + (size_t)(kt + 1) * 64 * HD;
      const u16* vb = Vh + (size_t)(kt + 1) * 64;
#pragma unroll
      for (int h = 0; h < 2; ++h) {
        krg[h] = *(const u32x4*)(kb + (size_t)(h * 32 + s_r) * HD + s_c);
        vrg[h] = *(const u32x4*)(vb + (size_t)(h * 32 + s_r) * SS + s_c);
      }
    }
    f32x4 st[4] = {};
#pragma unroll
    for (int ks = 0; ks < 2; ++ks) {
      bf16x8 qf = ks ? qf1 : qf0;
      int kk = ks * 32 + g * 8;
#pragma unroll
      for (int t = 0; t < 4; ++t) {
        bf16x8 kf = *(const bf16x8*)(&Ks[cur][t * 16 + lq][kk]);
        st[t] = __builtin_amdgcn_mfma_f32_16x16x32_bf16(kf, qf, st[t], 0, 0, 0);
      }
    }
    // pa = exp2(st) UNNORMALIZED (bounded); ps accumulates
    alignas(16) bf16x4 pb[4];
#pragma unroll
    for (int t = 0; t < 4; ++t) {
      f32x4 p;
#pragma unroll
      for (int i = 0; i < 4; ++i) {
        p[i] = __builtin_amdgcn_exp2f(st[t][i]);
        ps += p[i];
      }
#pragma unroll
      for (int i = 0; i < 4; ++i) pb[t][i] = (short)f2bf_fast(p[i]);
    }
#pragma unroll
    for (int c = 0; c < 2; ++c) {
      bf16x8 pa = *(const bf16x8*)(&pb[2 * c]);
#pragma unroll
      for (int nt = 0; nt < 4; ++nt) {
        bf16x8 vf = *(const bf16x8*)(&Vs[cur][nt * 16 + lq][c * 32 + g * 8]);
        accv[nt] = __builtin_amdgcn_mfma_f32_16x16x32_bf16(vf, pa, accv[nt], 0, 0, 0);
      }
    }
    if (kt < 31) {
#pragma unroll
      for (int h = 0; h < 2; ++h) {
        *(u32x4*)(&Ks[cur ^ 1][h * 32 + s_r][s_c]) = krg[h];
        *(u32x4*)(&Vs[cur ^ 1][h * 32 + s_r][s_c]) = vrg[h];
      }
    }
    LDS_BARRIER();
  }

  ps += __shfl_xor(ps, 16);
  ps += __shfl_xor(ps, 32);
  float rinv = 1.0f / ps;
  // v_log_f32 IS log2 -> nb = -log2(ps)
  if (lane < 16)
    nbuf[(size_t)bh * SS + qt * 64 + wv * 16 + lq] = -__builtin_amdgcn_logf(ps);

  u16* Ah = Att + (size_t)bh * HELEM + (qt * 64 + wv * 16) * HD;
#pragma unroll
  for (int nt = 0; nt < 4; ++nt) {
    bf16x4 ob;
#pragma unroll
    for (int i = 0; i < 4; ++i) ob[i] = (short)f2bf(accv[nt][i] * rinv);
    *(bf16x4*)(Ah + (size_t)lq * HD + nt * 16 + g * 4) = ob;
  }
}

// ---------------- P writer: pure store stream ----------------
// Block = (key-slice of 128, q-half, head): grid 1024 = 4 blocks/CU (deep
// aggregate store queue). K slice (16 KB) reg-staged into PADDED LDS once
// (8-way banks instead of linear's 16-way); each of the 8 waves owns 128
// q-rows whose Q-fragments + nb live ENTIRELY in registers (full unroll ->
// static indexing). The main loop's only VMEM ops are the P-stores -> no
// vmcnt load-waits ever drain the stream; it runs at HBM pace.
__global__ __launch_bounds__(512, 2) void p_write(
    const u16* __restrict__ Kb, const u16* __restrict__ Qb,
    const float* __restrict__ nbuf, float* __restrict__ attn_out) {
  __shared__ u16 Ks[128][72];  // padded
  int tid = threadIdx.x, lane = tid & 63, wv = tid >> 6;
  int g = lane >> 4, lq = lane & 15;
  int e = blockIdx.x >> 1, qh = blockIdx.x & 1, bh = blockIdx.y;
  const u16* Kh = Kb + (size_t)bh * HELEM + (size_t)e * 128 * HD;
  const u16* Qh = Qb + (size_t)bh * HELEM;
  float* aout = attn_out + (size_t)bh * SS * SS + e * 128;

  // reg-stage K slice 128x64 -> padded LDS (2 rounds of 512 x 16B)
  int s_r = tid >> 3, s_c = (tid & 7) * 8;
#pragma unroll
  for (int h = 0; h < 2; ++h) {
    u32x4 v = *(const u32x4*)(Kh + (size_t)(h * 64 + s_r) * HD + s_c);
    *(u32x4*)(&Ks[h * 64 + s_r][s_c]) = v;
  }
  // preload this wave's 128 q-rows of Q-fragments + nb into registers
  int q0 = qh * 1024 + wv * 128;
  bf16x8 qf[8][2];
  float nbq[8];
#pragma unroll
  for (int qi = 0; qi < 8; ++qi) {
#pragma unroll
    for (int ks = 0; ks < 2; ++ks)
      qf[qi][ks] = *(const bf16x8*)(Qh + (size_t)(q0 + qi * 16 + lq) * HD +
                                    ks * 32 + g * 8);
    nbq[qi] = nbuf[(size_t)bh * SS + q0 + qi * 16 + lq];
  }
  __syncthreads();  // drains prologue VMEM once

  // pure store-stream loop (static qf/nbq indices via full unroll)
#pragma unroll
  for (int qi = 0; qi < 8; ++qi) {
    f32x4 nbv = {nbq[qi], nbq[qi], nbq[qi], nbq[qi]};
    float* arow = aout + (size_t)(q0 + qi * 16 + lq) * SS;
#pragma unroll
    for (int kc = 0; kc < 2; ++kc) {
      f32x4 st[4] = {nbv, nbv, nbv, nbv};
#pragma unroll
      for (int ks = 0; ks < 2; ++ks)
#pragma unroll
        for (int t = 0; t < 4; ++t) {
          bf16x8 kf = *(const bf16x8*)(
              &Ks[kc * 64 + t * 16 + lq][ks * 32 + g * 8]);
          st[t] = __builtin_amdgcn_mfma_f32_16x16x32_bf16(kf, qf[qi][ks],
                                                          st[t], 0, 0, 0);
        }
#pragma unroll
      for (int t = 0; t < 4; ++t) {
        f32x4 p;
#pragma unroll
        for (int i = 0; i < 4; ++i) p[i] = __builtin_amdgcn_exp2f(st[t][i]);
        *(f32x4*)(arow + kc * 64 + t * 16 + g * 4) = p;
      }
    }
  }
}

// ---------------- host launch ----------------
extern "C" void kernel_launch(void* const* d_in, const int* in_sizes, int n_in,
                              void* d_out, int out_size, void* d_ws,
                              size_t ws_size, hipStream_t stream) {
  const float* inputs  = (const float*)d_in[0];
  const float* context = (const float*)d_in[1];
  const float* Wq = (const float*)d_in[2];
  const float* bq = (const float*)d_in[3];
  const float* Wk = (const float*)d_in[4];
  const float* bk = (const float*)d_in[5];
  const float* Wv = (const float*)d_in[6];
  const float* bv = (const float*)d_in[7];
  const float* Wo = (const float*)d_in[8];
  const float* bo = (const float*)d_in[9];
  float* out = (float*)d_out;
  float* attn = out + (size_t)BS * HH;

  char* ws = (char*)d_ws;
  u16* Xbf = (u16*)(ws + 0);          // 8 MB
  u16* Cbf = (u16*)(ws + 8388608);    // 8 MB
  u16* WqT = (u16*)(ws + 16777216);   // 2 MB each
  u16* WkT = (u16*)(ws + 18874368);
  u16* WvT = (u16*)(ws + 20971520);
  u16* WoT = (u16*)(ws + 23068672);
  u16* Qb  = (u16*)(ws + 25165824);   // 8 MB
  u16* Kb  = (u16*)(ws + 33554432);   // 8 MB
  u16* Vb  = (u16*)(ws + 41943040);   // 8 MB
  u16* Vtb = Cbf;                         // reuse: Cbf dead after qkv_gemm
  float* nbuf = (float*)(ws + 18874368);  // reuse WkT slot (dead after qkv)
  u16* Attb = Xbf;                        // reuse: Xbf dead after qkv

  cvt_inputs<<<dim3(2048), dim3(256), 0, stream>>>(inputs, context, Xbf, Cbf);
  cvt_transpose_w<<<dim3(16, 16, 4), dim3(256), 0, stream>>>(
      Wq, Wk, Wv, Wo, WqT, WkT, WvT, WoT);
  qkv_gemm<<<dim3(8, 32, 3), dim3(256), 0, stream>>>(
      Xbf, Cbf, WqT, WkT, WvT, bq, bk, bv, Qb, Kb, Vb);
  vtrans<<<dim3(32, 32), dim3(256), 0, stream>>>(Vb, Vtb);
  attn_core<<<dim3(32, 32), dim3(256), 0, stream>>>(Qb, Kb, Vtb, nbuf, Attb);
  p_write<<<dim3(32, 32), dim3(512), 0, stream>>>(Kb, Qb, nbuf, attn);
  out_gemm<<<dim3(8, 32), dim3(256), 0, stream>>>(Attb, WoT, bo, out);
}

// Round 12
// 264.139 us; speedup vs baseline: 1.7685x; 1.0127x over previous
//
#include <hip/hip_runtime.h>

#define DEVI __device__ __forceinline__

typedef short bf16x8 __attribute__((ext_vector_type(8)));
typedef short bf16x4 __attribute__((ext_vector_type(4)));
typedef float f32x4 __attribute__((ext_vector_type(4)));
typedef unsigned int u32x4 __attribute__((ext_vector_type(4)));
typedef unsigned short u16;

static constexpr int BB = 2, SS = 2048, HH = 1024, HD = 64;
static constexpr int BS = BB * SS;        // 4096 rows
static constexpr int HELEM = SS * HD;     // 131072 elems per head slice
// Q pre-scale: scores come out of MFMA in exp2 units: s*(1/32)*log2(e)
static constexpr float SC2Q = 0.045084220063365596f;

DEVI u16 f2bf(float f) {
  union { float f; unsigned u; } v; v.f = f;
  unsigned r = v.u + 0x7fffu + ((v.u >> 16) & 1u);
  return (u16)(r >> 16);
}
DEVI u16 f2bf_fast(float f) {  // round-half-up (1 fewer VALU op)
  union { float f; unsigned u; } v; v.f = f;
  return (u16)((v.u + 0x8000u) >> 16);
}

// async global->LDS, 16B per lane; lds ptr must be wave-uniform
DEVI void gl16(const u16* g, u16* l) {
  __builtin_amdgcn_global_load_lds(
      (const __attribute__((address_space(1))) unsigned int*)g,
      (__attribute__((address_space(3))) unsigned int*)l, 16, 0, 0);
}

// raw barrier: wait LDS ops only — NEVER drains vmcnt
#define LDS_BARRIER() asm volatile("s_waitcnt lgkmcnt(0)\n\ts_barrier" ::: "memory")

// ---------------- f32 -> bf16 converters ----------------
__global__ __launch_bounds__(256) void cvt_inputs(const float* __restrict__ a,
                                                  const float* __restrict__ b,
                                                  u16* __restrict__ oa,
                                                  u16* __restrict__ ob) {
  const int NV = BS * HH / 4;
  int stride = gridDim.x * blockDim.x;
  for (int idx = blockIdx.x * blockDim.x + threadIdx.x; idx < 2 * NV; idx += stride) {
    int which = idx >= NV;
    int e = (which ? idx - NV : idx) * 4;
    const float* src = which ? b : a;
    u16* dst = which ? ob : oa;
    f32x4 v = *(const f32x4*)(src + e);
    unsigned long long pk = (unsigned long long)f2bf(v[0]) |
                            ((unsigned long long)f2bf(v[1]) << 16) |
                            ((unsigned long long)f2bf(v[2]) << 32) |
                            ((unsigned long long)f2bf(v[3]) << 48);
    *(unsigned long long*)(dst + e) = pk;
  }
}

// W [K,N] f32 -> WT [N,K] bf16
__global__ __launch_bounds__(256) void cvt_transpose_w(
    const float* __restrict__ w0, const float* __restrict__ w1,
    const float* __restrict__ w2, const float* __restrict__ w3,
    u16* __restrict__ t0, u16* __restrict__ t1, u16* __restrict__ t2,
    u16* __restrict__ t3) {
  const float* W; u16* T;
  switch (blockIdx.z) {
    case 0: W = w0; T = t0; break;
    case 1: W = w1; T = t1; break;
    case 2: W = w2; T = t2; break;
    default: W = w3; T = t3; break;
  }
  __shared__ float tile[64][65];
  int t = threadIdx.x;
  int bx = blockIdx.x, by = blockIdx.y;
  for (int h = 0; h < 4; ++h) {
    int r = (t >> 4) + h * 16;
    int c0 = (t & 15) * 4;
    f32x4 v = *(const f32x4*)(W + (size_t)(by * 64 + r) * HH + bx * 64 + c0);
    tile[r][c0 + 0] = v[0]; tile[r][c0 + 1] = v[1];
    tile[r][c0 + 2] = v[2]; tile[r][c0 + 3] = v[3];
  }
  __syncthreads();
  for (int h = 0; h < 4; ++h) {
    int nr = (t >> 4) + h * 16;
    int kc0 = (t & 15) * 4;
    unsigned long long pk = 0;
    for (int j = 0; j < 4; ++j)
      pk |= (unsigned long long)f2bf(tile[kc0 + j][nr]) << (16 * j);
    *(unsigned long long*)(T + (size_t)(bx * 64 + nr) * HH + by * 64 + kc0) = pk;
  }
}

// ------- 128x128 tile bf16 GEMM, global_load_lds staging (m97 pattern) -------
// OUTMODE: 0 = bf16 row-major, 1 = f32 row-major, 2 = bf16*SC2Q row-major
template <int OUTMODE>
DEVI void gemm_body(const u16* __restrict__ A, const u16* __restrict__ BT,
                    const float* __restrict__ bias, void* __restrict__ Cout,
                    int N, int K, int bm, int bn) {
  __shared__ u16 As[128 * 64];  // linear: row*64 + col (gload_lds requires)
  __shared__ u16 Bs[128 * 64];
  int tid = threadIdx.x, lane = tid & 63, wv = tid >> 6;
  int wr = wv >> 1, wc = wv & 1;
  int lq = lane & 15, g = lane >> 4;
  f32x4 acc[4][4] = {};
  const u16* Ab = A + (size_t)bm * 128 * K;
  const u16* Bb = BT + (size_t)bn * 128 * K;
  int srow = lane >> 3;
  int scol = (lane & 7) * 8;

  for (int k0 = 0; k0 < K; k0 += 64) {
#pragma unroll
    for (int h = 0; h < 4; ++h) {
      int ch = wv * 4 + h;
      int row = ch * 8 + srow;
      gl16(Ab + (size_t)row * K + k0 + scol, &As[ch * 512]);
      gl16(Bb + (size_t)row * K + k0 + scol, &Bs[ch * 512]);
    }
    __syncthreads();
#pragma unroll
    for (int ks = 0; ks < 2; ++ks) {
      int kk = ks * 32 + g * 8;
      bf16x8 af[4], bfr[4];
#pragma unroll
      for (int mt = 0; mt < 4; ++mt)
        af[mt] = *(const bf16x8*)(&As[(wr * 64 + mt * 16 + lq) * 64 + kk]);
#pragma unroll
      for (int nt = 0; nt < 4; ++nt)
        bfr[nt] = *(const bf16x8*)(&Bs[(wc * 64 + nt * 16 + lq) * 64 + kk]);
#pragma unroll
      for (int mt = 0; mt < 4; ++mt)
#pragma unroll
        for (int nt = 0; nt < 4; ++nt)
          acc[mt][nt] = __builtin_amdgcn_mfma_f32_16x16x32_bf16(
              af[mt], bfr[nt], acc[mt][nt], 0, 0, 0);
    }
    __syncthreads();
  }
#pragma unroll
  for (int mt = 0; mt < 4; ++mt)
#pragma unroll
    for (int nt = 0; nt < 4; ++nt) {
      int col = bn * 128 + wc * 64 + nt * 16 + lq;
      float bv = bias[col];
#pragma unroll
      for (int i = 0; i < 4; ++i) {
        int row = bm * 128 + wr * 64 + mt * 16 + g * 4 + i;
        float v = acc[mt][nt][i] + bv;
        if (OUTMODE == 1)
          ((float*)Cout)[(size_t)row * N + col] = v;
        else if (OUTMODE == 2)
          ((u16*)Cout)[(size_t)row * N + col] = f2bf(v * SC2Q);
        else
          ((u16*)Cout)[(size_t)row * N + col] = f2bf(v);
      }
    }
}

__global__ __launch_bounds__(256, 3) void qkv_gemm(
    const u16* __restrict__ X, const u16* __restrict__ C,
    const u16* __restrict__ WqT, const u16* __restrict__ WkT,
    const u16* __restrict__ WvT, const float* __restrict__ bq,
    const float* __restrict__ bk, const float* __restrict__ bv,
    u16* __restrict__ Qo, u16* __restrict__ Ko, u16* __restrict__ Vo) {
  if (blockIdx.z == 0)
    gemm_body<2>(X, WqT, bq, Qo, HH, HH, blockIdx.y, blockIdx.x);
  else if (blockIdx.z == 1)
    gemm_body<0>(C, WkT, bk, Ko, HH, HH, blockIdx.y, blockIdx.x);
  else
    gemm_body<0>(C, WvT, bv, Vo, HH, HH, blockIdx.y, blockIdx.x);
}

__global__ __launch_bounds__(256, 3) void out_gemm(const u16* __restrict__ Att,
                                                   const u16* __restrict__ WoT,
                                                   const float* __restrict__ bo,
                                                   float* __restrict__ out) {
  gemm_body<1>(Att, WoT, bo, out, HH, HH, blockIdx.y, blockIdx.x);
}

// ---------------- per-head permuted V transpose ----------------
// Vt2[d][sigma] = V_head[kappa(sigma)][d]; within each 32-key chunk,
// kappa: sigma = 32c+8g+j -> 32c + 16*(j>>2) + 4*g + (j&3).
__global__ __launch_bounds__(256) void vtrans(const u16* __restrict__ V,
                                              u16* __restrict__ Vt2) {
  int head = blockIdx.y, kt = blockIdx.x;
  __shared__ u16 tile[64][72];
  int t = threadIdx.x;
  const u16* src = V + (size_t)head * HELEM + kt * 64 * HD;
  for (int h = 0; h < 2; ++h) {
    int r = (t >> 3) + h * 32;
    int c0 = (t & 7) * 8;
    *(u32x4*)(&tile[r][c0]) = *(const u32x4*)(src + r * HD + c0);
  }
  __syncthreads();
  u16* dst = Vt2 + (size_t)head * HELEM;
  for (int h = 0; h < 2; ++h) {
    int d = (t >> 3) + h * 32;
    int s0 = (t & 7) * 8;
    int base32 = s0 & ~31, g = (s0 >> 3) & 3;
    u16 tmp[8];
#pragma unroll
    for (int j = 0; j < 8; ++j)
      tmp[j] = tile[base32 + 16 * (j >> 2) + 4 * g + (j & 3)][d];
    *(u32x4*)(dst + (size_t)d * SS + kt * 64 + s0) = *(u32x4*)tmp;
  }
}

// ---------- attention core: single pass, NO P-store, 2 q-groups/wave -------
// 128 q-rows/block (each wave: groups at +0 and +16 of its 32-row span).
// K/V fragments are read ONCE and feed BOTH groups' MFMAs -> per-iteration
// compute doubles against the same load+barrier latency; grid halves to 512
// (half the per-head K/V re-reads). KVBLK=64, LDS 36 KB, 3 blocks/CU.
__global__ __launch_bounds__(256, 3) void attn_core(
    const u16* __restrict__ Q, const u16* __restrict__ K,
    const u16* __restrict__ Vt2, float* __restrict__ nbuf,
    u16* __restrict__ Att) {
  __shared__ u16 Ks[2][64][72];
  __shared__ u16 Vs[2][64][72];
  int tid = threadIdx.x, lane = tid & 63, wv = tid >> 6;
  int g = lane >> 4, lq = lane & 15;
  int qt = blockIdx.x, bh = blockIdx.y;
  const u16* Qh = Q + (size_t)bh * HELEM + (qt * 128 + wv * 32) * HD;
  const u16* Kh = K + (size_t)bh * HELEM;
  const u16* Vh = Vt2 + (size_t)bh * HELEM;

  // Q fragments for both 16-row groups (already in exp2 units)
  bf16x8 qf[2][2];
#pragma unroll
  for (int grp = 0; grp < 2; ++grp)
#pragma unroll
    for (int ks = 0; ks < 2; ++ks)
      qf[grp][ks] =
          *(const bf16x8*)(Qh + (size_t)(grp * 16 + lq) * HD + ks * 32 + g * 8);

  int s_r = tid >> 3, s_c = (tid & 7) * 8;  // K/V stage: rows s_r + h*32
  u32x4 krg[2], vrg[2];

  f32x4 accv0[4] = {}, accv1[4] = {};
  float ps0 = 0.0f, ps1 = 0.0f;
#pragma unroll
  for (int h = 0; h < 2; ++h) {
    krg[h] = *(const u32x4*)(Kh + (size_t)(h * 32 + s_r) * HD + s_c);
    vrg[h] = *(const u32x4*)(Vh + (size_t)(h * 32 + s_r) * SS + s_c);
  }
#pragma unroll
  for (int h = 0; h < 2; ++h) {
    *(u32x4*)(&Ks[0][h * 32 + s_r][s_c]) = krg[h];
    *(u32x4*)(&Vs[0][h * 32 + s_r][s_c]) = vrg[h];
  }
  LDS_BARRIER();

  for (int kt = 0; kt < 32; ++kt) {
    int cur = kt & 1;
    if (kt < 31) {
      const u16* kb = Kh + (size_t)(kt + 1) * 64 * HD;
      const u16* vb = Vh + (size_t)(kt + 1) * 64;
#pragma unroll
      for (int h = 0; h < 2; ++h) {
        krg[h] = *(const u32x4*)(kb + (size_t)(h * 32 + s_r) * HD + s_c);
        vrg[h] = *(const u32x4*)(vb + (size_t)(h * 32 + s_r) * SS + s_c);
      }
    }
    f32x4 st0[4] = {}, st1[4] = {};
#pragma unroll
    for (int ks = 0; ks < 2; ++ks) {
      int kk = ks * 32 + g * 8;
#pragma unroll
      for (int t = 0; t < 4; ++t) {
        bf16x8 kf = *(const bf16x8*)(&Ks[cur][t * 16 + lq][kk]);
        st0[t] = __builtin_amdgcn_mfma_f32_16x16x32_bf16(kf, qf[0][ks], st0[t], 0, 0, 0);
        st1[t] = __builtin_amdgcn_mfma_f32_16x16x32_bf16(kf, qf[1][ks], st1[t], 0, 0, 0);
      }
    }
    // p = exp2(st) UNNORMALIZED (bounded); ps accumulates
    alignas(16) bf16x4 pb0[4], pb1[4];
#pragma unroll
    for (int t = 0; t < 4; ++t) {
      f32x4 p0, p1;
#pragma unroll
      for (int i = 0; i < 4; ++i) {
        p0[i] = __builtin_amdgcn_exp2f(st0[t][i]);
        p1[i] = __builtin_amdgcn_exp2f(st1[t][i]);
        ps0 += p0[i];
        ps1 += p1[i];
      }
#pragma unroll
      for (int i = 0; i < 4; ++i) {
        pb0[t][i] = (short)f2bf_fast(p0[i]);
        pb1[t][i] = (short)f2bf_fast(p1[i]);
      }
    }
#pragma unroll
    for (int c = 0; c < 2; ++c) {
      bf16x8 pa0 = *(const bf16x8*)(&pb0[2 * c]);
      bf16x8 pa1 = *(const bf16x8*)(&pb1[2 * c]);
#pragma unroll
      for (int nt = 0; nt < 4; ++nt) {
        bf16x8 vf = *(const bf16x8*)(&Vs[cur][nt * 16 + lq][c * 32 + g * 8]);
        accv0[nt] = __builtin_amdgcn_mfma_f32_16x16x32_bf16(vf, pa0, accv0[nt], 0, 0, 0);
        accv1[nt] = __builtin_amdgcn_mfma_f32_16x16x32_bf16(vf, pa1, accv1[nt], 0, 0, 0);
      }
    }
    if (kt < 31) {
#pragma unroll
      for (int h = 0; h < 2; ++h) {
        *(u32x4*)(&Ks[cur ^ 1][h * 32 + s_r][s_c]) = krg[h];
        *(u32x4*)(&Vs[cur ^ 1][h * 32 + s_r][s_c]) = vrg[h];
      }
    }
    LDS_BARRIER();
  }

  ps0 += __shfl_xor(ps0, 16); ps0 += __shfl_xor(ps0, 32);
  ps1 += __shfl_xor(ps1, 16); ps1 += __shfl_xor(ps1, 32);
  float rinv0 = 1.0f / ps0, rinv1 = 1.0f / ps1;
  // v_log_f32 IS log2 -> nb = -log2(ps)
  if (lane < 16) {
    size_t nrow = (size_t)bh * SS + qt * 128 + wv * 32 + lq;
    nbuf[nrow] = -__builtin_amdgcn_logf(ps0);
    nbuf[nrow + 16] = -__builtin_amdgcn_logf(ps1);
  }

  u16* Ah = Att + (size_t)bh * HELEM + (qt * 128 + wv * 32) * HD;
#pragma unroll
  for (int nt = 0; nt < 4; ++nt) {
    bf16x4 ob0, ob1;
#pragma unroll
    for (int i = 0; i < 4; ++i) {
      ob0[i] = (short)f2bf(accv0[nt][i] * rinv0);
      ob1[i] = (short)f2bf(accv1[nt][i] * rinv1);
    }
    *(bf16x4*)(Ah + (size_t)lq * HD + nt * 16 + g * 4) = ob0;
    *(bf16x4*)(Ah + (size_t)(16 + lq) * HD + nt * 16 + g * 4) = ob1;
  }
}

// ---------------- P writer: pure store stream ----------------
// Block = (key-slice of 128, q-quarter of 512, head): grid 2048. Each wave
// owns 64 q-rows (qf[4][2] = 32 VGPR) -> ~90 VGPR total; launch_bounds(512,4)
// caps regs at 128 so 2 blocks/CU (16 waves, 4/SIMD) genuinely fit. K slice
// (16 KB) reg-staged into PADDED LDS once. The main loop's only VMEM ops are
// the P-stores -> no vmcnt load-waits ever drain the stream.
__global__ __launch_bounds__(512, 4) void p_write(
    const u16* __restrict__ Kb, const u16* __restrict__ Qb,
    const float* __restrict__ nbuf, float* __restrict__ attn_out) {
  __shared__ u16 Ks[128][72];  // padded
  int tid = threadIdx.x, lane = tid & 63, wv = tid >> 6;
  int g = lane >> 4, lq = lane & 15;
  int e = blockIdx.x & 15, qq = blockIdx.x >> 4, bh = blockIdx.y;
  const u16* Kh = Kb + (size_t)bh * HELEM + (size_t)e * 128 * HD;
  const u16* Qh = Qb + (size_t)bh * HELEM;
  float* aout = attn_out + (size_t)bh * SS * SS + e * 128;

  // reg-stage K slice 128x64 -> padded LDS (2 rounds of 512 x 16B)
  int s_r = tid >> 3, s_c = (tid & 7) * 8;
#pragma unroll
  for (int h = 0; h < 2; ++h) {
    u32x4 v = *(const u32x4*)(Kh + (size_t)(h * 64 + s_r) * HD + s_c);
    *(u32x4*)(&Ks[h * 64 + s_r][s_c]) = v;
  }
  // preload this wave's 64 q-rows of Q-fragments + nb into registers
  int q0 = qq * 512 + wv * 64;
  bf16x8 qf[4][2];
  float nbq[4];
#pragma unroll
  for (int qi = 0; qi < 4; ++qi) {
#pragma unroll
    for (int ks = 0; ks < 2; ++ks)
      qf[qi][ks] = *(const bf16x8*)(Qh + (size_t)(q0 + qi * 16 + lq) * HD +
                                    ks * 32 + g * 8);
    nbq[qi] = nbuf[(size_t)bh * SS + q0 + qi * 16 + lq];
  }
  __syncthreads();  // drains prologue VMEM once

  // pure store-stream loop (static qf/nbq indices via full unroll)
#pragma unroll
  for (int qi = 0; qi < 4; ++qi) {
    f32x4 nbv = {nbq[qi], nbq[qi], nbq[qi], nbq[qi]};
    float* arow = aout + (size_t)(q0 + qi * 16 + lq) * SS;
#pragma unroll
    for (int kc = 0; kc < 2; ++kc) {
      f32x4 st[4] = {nbv, nbv, nbv, nbv};
#pragma unroll
      for (int ks = 0; ks < 2; ++ks)
#pragma unroll
        for (int t = 0; t < 4; ++t) {
          bf16x8 kf = *(const bf16x8*)(
              &Ks[kc * 64 + t * 16 + lq][ks * 32 + g * 8]);
          st[t] = __builtin_amdgcn_mfma_f32_16x16x32_bf16(kf, qf[qi][ks],
                                                          st[t], 0, 0, 0);
        }
#pragma unroll
      for (int t = 0; t < 4; ++t) {
        f32x4 p;
#pragma unroll
        for (int i = 0; i < 4; ++i) p[i] = __builtin_amdgcn_exp2f(st[t][i]);
        *(f32x4*)(arow + kc * 64 + t * 16 + g * 4) = p;
      }
    }
  }
}

// ---------------- host launch ----------------
extern "C" void kernel_launch(void* const* d_in, const int* in_sizes, int n_in,
                              void* d_out, int out_size, void* d_ws,
                              size_t ws_size, hipStream_t stream) {
  const float* inputs  = (const float*)d_in[0];
  const float* context = (const float*)d_in[1];
  const float* Wq = (const float*)d_in[2];
  const float* bq = (const float*)d_in[3];
  const float* Wk = (const float*)d_in[4];
  const float* bk = (const float*)d_in[5];
  const float* Wv = (const float*)d_in[6];
  const float* bv = (const float*)d_in[7];
  const float* Wo = (const float*)d_in[8];
  const float* bo = (const float*)d_in[9];
  float* out = (float*)d_out;
  float* attn = out + (size_t)BS * HH;

  char* ws = (char*)d_ws;
  u16* Xbf = (u16*)(ws + 0);          // 8 MB
  u16* Cbf = (u16*)(ws + 8388608);    // 8 MB
  u16* WqT = (u16*)(ws + 16777216);   // 2 MB each
  u16* WkT = (u16*)(ws + 18874368);
  u16* WvT = (u16*)(ws + 20971520);
  u16* WoT = (u16*)(ws + 23068672);
  u16* Qb  = (u16*)(ws + 25165824);   // 8 MB
  u16* Kb  = (u16*)(ws + 33554432);   // 8 MB
  u16* Vb  = (u16*)(ws + 41943040);   // 8 MB
  u16* Vtb = Cbf;                         // reuse: Cbf dead after qkv_gemm
  float* nbuf = (float*)(ws + 18874368);  // reuse WkT slot (dead after qkv)
  u16* Attb = Xbf;                        // reuse: Xbf dead after qkv

  cvt_inputs<<<dim3(2048), dim3(256), 0, stream>>>(inputs, context, Xbf, Cbf);
  cvt_transpose_w<<<dim3(16, 16, 4), dim3(256), 0, stream>>>(
      Wq, Wk, Wv, Wo, WqT, WkT, WvT, WoT);
  qkv_gemm<<<dim3(8, 32, 3), dim3(256), 0, stream>>>(
      Xbf, Cbf, WqT, WkT, WvT, bq, bk, bv, Qb, Kb, Vb);
  vtrans<<<dim3(32, 32), dim3(256), 0, stream>>>(Vb, Vtb);
  attn_core<<<dim3(16, 32), dim3(256), 0, stream>>>(Qb, Kb, Vtb, nbuf, Attb);
  p_write<<<dim3(64, 32), dim3(512), 0, stream>>>(Kb, Qb, nbuf, attn);
  out_gemm<<<dim3(8, 32), dim3(256), 0, stream>>>(Attb, WoT, bo, out);
}